// Round 1
// baseline (515.322 us; speedup 1.0000x reference)
//
#include <hip/hip_runtime.h>
#include <stdint.h>

typedef __attribute__((ext_vector_type(4))) float f32x4;
typedef __attribute__((ext_vector_type(8))) short short8;
typedef unsigned short u16;
typedef unsigned int u32;

#define DEV static __device__ __forceinline__

DEV u32 fbits(float f) { union { float f; u32 u; } v; v.f = f; return v.u; }
DEV float bits2f(u32 u) { union { u32 u; float f; } v; v.u = u; return v.f; }

// bf16 round-to-nearest-even
DEV u16 f2bf_rne(float f) {
  u32 u = fbits(f);
  u32 r = u + 0x7fffu + ((u >> 16) & 1u);
  return (u16)(r >> 16);
}
DEV u16 f2bf_trunc(float f) { return (u16)(fbits(f) >> 16); }
DEV float bf2f(u16 h) { return bits2f(((u32)h) << 16); }

// split f32 -> hi (RNE) + lo (trunc of residual): hi+lo accurate to ~2^-15 rel
DEV void split2(float f, u16& h, u16& l) {
  h = f2bf_rne(f);
  float r = f - bf2f(h);
  l = f2bf_trunc(r);
}

DEV void gll16(const void* gsrc, char* ldsp) {
  __builtin_amdgcn_global_load_lds(
      (const __attribute__((address_space(1))) u32*)gsrc,
      (__attribute__((address_space(3))) u32*)ldsp,
      16, 0, 0);
}

DEV f32x4 mfma16(short8 a, short8 b, f32x4 c) {
  return __builtin_amdgcn_mfma_f32_16x16x32_bf16(a, b, c, 0, 0, 0);
}

// ---------------------------------------------------------------------------
// K1: C[M][N] = A[M][512] * B[N][512]^T in fp32-emulated (split bf16, 3 MFMA)
// EPI==0: write (scale*C) split into hi/lo bf16 arrays [M][512]   (q, k)
// EPI==1: write bf16(C) into v_t[b][d][s] layout, m=d, n=global token (v)
// block 256 thr (4 waves), tile 128x128, BK=64, LDS 64KiB
// ---------------------------------------------------------------------------
template<int EPI>
__global__ __launch_bounds__(256, 1) void proj_gemm(
    const float* __restrict__ A, const float* __restrict__ Bm,
    u16* __restrict__ o0, u16* __restrict__ o1, float scale)
{
  extern __shared__ char smem[];
  const int tid = threadIdx.x;
  const int lane = tid & 63, wv = tid >> 6;
  const int wm = wv & 1, wn = wv >> 1;
  const int lm = lane & 15, lg = lane >> 4;
  const int n0 = blockIdx.x * 128, m0 = blockIdx.y * 128;

  f32x4 acc[4][4] = {};

  for (int k0 = 0; k0 < 512; k0 += 64) {
    __syncthreads();
    // stage A,B 128x64 f32 tiles -> hi/lo bf16 LDS, swizzled (chunk ^= row&7)
    #pragma unroll
    for (int i = 0; i < 8; ++i) {
      int c = i * 256 + tid;          // f32x4 chunk 0..2047
      int row = c >> 4, c4 = c & 15;
      f32x4 av = *(const f32x4*)(A + (size_t)(m0 + row) * 512 + (k0 + c4 * 4));
      f32x4 bv = *(const f32x4*)(Bm + (size_t)(n0 + row) * 512 + (k0 + c4 * 4));
      int base = row * 128 + ((((c4 >> 1) ^ (row & 7)) << 4) + (c4 & 1) * 8);
      u16 ah[4], al[4], bh[4], bl[4];
      #pragma unroll
      for (int j = 0; j < 4; ++j) { split2(av[j], ah[j], al[j]); split2(bv[j], bh[j], bl[j]); }
      *(ushort4*)(smem +         base) = make_ushort4(ah[0], ah[1], ah[2], ah[3]);
      *(ushort4*)(smem + 16384 + base) = make_ushort4(al[0], al[1], al[2], al[3]);
      *(ushort4*)(smem + 32768 + base) = make_ushort4(bh[0], bh[1], bh[2], bh[3]);
      *(ushort4*)(smem + 49152 + base) = make_ushort4(bl[0], bl[1], bl[2], bl[3]);
    }
    __syncthreads();
    #pragma unroll
    for (int ks = 0; ks < 2; ++ks) {
      short8 fah[4], fal[4], fbh[4], fbl[4];
      #pragma unroll
      for (int t = 0; t < 4; ++t) {
        int ar = wm * 64 + t * 16 + lm;
        int ac = (((ks * 4 + lg) ^ (ar & 7)) << 4);
        fah[t] = *(const short8*)(smem +         ar * 128 + ac);
        fal[t] = *(const short8*)(smem + 16384 + ar * 128 + ac);
        int br = wn * 64 + t * 16 + lm;
        int bc = (((ks * 4 + lg) ^ (br & 7)) << 4);
        fbh[t] = *(const short8*)(smem + 32768 + br * 128 + bc);
        fbl[t] = *(const short8*)(smem + 49152 + br * 128 + bc);
      }
      #pragma unroll
      for (int mt = 0; mt < 4; ++mt)
        #pragma unroll
        for (int nt = 0; nt < 4; ++nt) {
          acc[mt][nt] = mfma16(fah[mt], fbh[nt], acc[mt][nt]);
          acc[mt][nt] = mfma16(fah[mt], fbl[nt], acc[mt][nt]);
          acc[mt][nt] = mfma16(fal[mt], fbh[nt], acc[mt][nt]);
        }
    }
  }
  // epilogue: C row = (lane>>4)*4 + i, col = lane&15  [m89-verified layout]
  #pragma unroll
  for (int mt = 0; mt < 4; ++mt)
    #pragma unroll
    for (int nt = 0; nt < 4; ++nt)
      #pragma unroll
      for (int i = 0; i < 4; ++i) {
        float v = acc[mt][nt][i] * scale;
        int m = m0 + wm * 64 + mt * 16 + lg * 4 + i;
        int n = n0 + wn * 64 + nt * 16 + lm;
        if (EPI == 0) {
          u16 h, l; split2(v, h, l);
          o0[(size_t)m * 512 + n] = h;
          o1[(size_t)m * 512 + n] = l;
        } else {
          // v_t[b][d][s]: b = n>>11, d = m, s = n&2047
          size_t addr = ((size_t)(n >> 11) << 20) | ((size_t)m << 11) | (size_t)(n & 2047);
          o0[addr] = f2bf_rne(v);
        }
      }
}

// ---------------------------------------------------------------------------
// K2: fused flash attention. block = 4 waves, 64 q-rows (16/wave), batch b.
// Q (hi,lo) resident in LDS; K tiles (64 keys x 64 d) streamed hi/lo;
// V^T tiles (64 d x 64 keys) streamed. Online softmax in-register per wave.
// Computes O^T[d][s] directly -> coalesced [B][D][S] store.
// LDS: QH 64K | QL 64K | KH 8K | KL 8K | VT 8K | P 8K = 160KiB exactly
// ---------------------------------------------------------------------------
#define QH_OFF 0
#define QL_OFF 65536
#define KH_OFF 131072
#define KL_OFF 139264
#define VT_OFF 147456
#define P_OFF  155648

__global__ __launch_bounds__(256, 1) void attn_fused(
    const u16* __restrict__ qh, const u16* __restrict__ ql,
    const u16* __restrict__ kh, const u16* __restrict__ kl,
    const u16* __restrict__ vt, float* __restrict__ out)
{
  extern __shared__ char smem[];
  const int tid = threadIdx.x;
  const int lane = tid & 63, wv = tid >> 6;
  const int lm = lane & 15, lg = lane >> 4;
  const int qt = blockIdx.x, b = blockIdx.y;

  // ---- stage Q hi/lo [64][512] bf16, swizzled (16B chunk ^= row&7)
  {
    const size_t qbase = (size_t)(b * 2048 + qt * 64) * 512;
    #pragma unroll
    for (int it = 0; it < 16; ++it) {
      int slot = it * 256 + tid;
      int row = slot >> 6, ch = slot & 63;
      int sc = ch ^ (row & 7);
      size_t src = qbase + (size_t)row * 512 + sc * 8;
      gll16(qh + src, smem + QH_OFF + slot * 16);
      gll16(ql + src, smem + QL_OFF + slot * 16);
    }
  }

  float mrow[4] = {-3e38f, -3e38f, -3e38f, -3e38f};
  float lrow[4] = {0.f, 0.f, 0.f, 0.f};
  f32x4 oacc[32] = {};

  const size_t kbase = (size_t)b * 2048 * 512;
  const size_t vbase = (size_t)b * 512 * 2048;
  const int qr = wv * 16 + lm;   // Q row this lane reads / P row / s-col

  for (int kt = 0; kt < 32; ++kt) {
    f32x4 sacc[4] = {};
    // ---- QK^T over d in 8 chunks of 64
    for (int dc = 0; dc < 8; ++dc) {
      __syncthreads();
      #pragma unroll
      for (int j = 0; j < 2; ++j) {   // stage K chunk [64 keys][64 d] hi+lo
        int slot = j * 256 + tid;
        int row = slot >> 3, ch = slot & 7;
        int sc = ch ^ (row & 7);
        size_t src = kbase + (size_t)(kt * 64 + row) * 512 + dc * 64 + sc * 8;
        gll16(kh + src, smem + KH_OFF + slot * 16);
        gll16(kl + src, smem + KL_OFF + slot * 16);
      }
      __syncthreads();
      #pragma unroll
      for (int ks = 0; ks < 2; ++ks) {
        int qc = (((dc * 8 + ks * 4 + lg) ^ (qr & 7)) << 4);
        short8 aqh = *(const short8*)(smem + QH_OFF + qr * 1024 + qc);
        short8 aql = *(const short8*)(smem + QL_OFF + qr * 1024 + qc);
        #pragma unroll
        for (int t4 = 0; t4 < 4; ++t4) {
          int krow = t4 * 16 + lm;
          int kc = (((ks * 4 + lg) ^ (krow & 7)) << 4);
          short8 bkh = *(const short8*)(smem + KH_OFF + krow * 128 + kc);
          short8 bkl = *(const short8*)(smem + KL_OFF + krow * 128 + kc);
          sacc[t4] = mfma16(aqh, bkh, sacc[t4]);
          sacc[t4] = mfma16(aqh, bkl, sacc[t4]);
          sacc[t4] = mfma16(aql, bkh, sacc[t4]);
        }
      }
    }
    // ---- online softmax; rows r = wv*16 + lg*4 + i, cols = t4*16 + lm.
    // Each wave owns rows == its s-cols, so P-LDS is wave-private (no barrier).
    float alpha[4];
    #pragma unroll
    for (int i = 0; i < 4; ++i) {
      float mx = fmaxf(fmaxf(sacc[0][i], sacc[1][i]), fmaxf(sacc[2][i], sacc[3][i]));
      mx = fmaxf(mx, __shfl_xor(mx, 1, 64));
      mx = fmaxf(mx, __shfl_xor(mx, 2, 64));
      mx = fmaxf(mx, __shfl_xor(mx, 4, 64));
      mx = fmaxf(mx, __shfl_xor(mx, 8, 64));
      float mn = fmaxf(mrow[i], mx);
      alpha[i] = __expf(mrow[i] - mn);
      mrow[i] = mn;
      int r = wv * 16 + lg * 4 + i;
      #pragma unroll
      for (int t4 = 0; t4 < 4; ++t4) {
        float p = __expf(sacc[t4][i] - mn);
        sacc[t4][i] = p;
        int col = t4 * 16 + lm;
        *(u16*)(smem + P_OFF + r * 128 +
                ((((col >> 3) ^ (r & 7)) << 4) | ((col & 7) << 1))) = f2bf_rne(p);
      }
      float sm = sacc[0][i] + sacc[1][i] + sacc[2][i] + sacc[3][i];
      sm += __shfl_xor(sm, 1, 64);
      sm += __shfl_xor(sm, 2, 64);
      sm += __shfl_xor(sm, 4, 64);
      sm += __shfl_xor(sm, 8, 64);
      lrow[i] = lrow[i] * alpha[i] + sm;
    }
    // redistribute alpha: this lane's s-col is lm -> alpha[lm&3] from group lm>>2
    {
      int src = (lm >> 2) << 4;
      float a0 = __shfl(alpha[0], src, 64);
      float a1 = __shfl(alpha[1], src, 64);
      float a2 = __shfl(alpha[2], src, 64);
      float a3 = __shfl(alpha[3], src, 64);
      int sel = lm & 3;
      float al = sel == 0 ? a0 : sel == 1 ? a1 : sel == 2 ? a2 : a3;
      #pragma unroll
      for (int f = 0; f < 32; ++f) {
        oacc[f][0] *= al; oacc[f][1] *= al; oacc[f][2] *= al; oacc[f][3] *= al;
      }
    }
    // P B-frags (wave-private region; compiler orders ds_write->ds_read)
    short8 pb0 = *(const short8*)(smem + P_OFF + qr * 128 + (((lg) ^ (qr & 7)) << 4));
    short8 pb1 = *(const short8*)(smem + P_OFF + qr * 128 + (((4 + lg) ^ (qr & 7)) << 4));
    // ---- PV: O^T[d][s] += V^T[d][k] * P[s][k], d streamed in 8 chunks of 64
    #pragma unroll
    for (int cv = 0; cv < 8; ++cv) {
      __syncthreads();
      #pragma unroll
      for (int j = 0; j < 2; ++j) {   // stage V^T chunk [64 d][64 keys]
        int slot = j * 256 + tid;
        int row = slot >> 3, ch = slot & 7;
        int sc = ch ^ (row & 7);
        size_t src = vbase + (size_t)(cv * 64 + row) * 2048 + kt * 64 + sc * 8;
        gll16(vt + src, smem + VT_OFF + slot * 16);
      }
      __syncthreads();
      #pragma unroll
      for (int dt = 0; dt < 4; ++dt) {
        int vr = dt * 16 + lm;
        short8 av0 = *(const short8*)(smem + VT_OFF + vr * 128 + (((lg) ^ (vr & 7)) << 4));
        short8 av1 = *(const short8*)(smem + VT_OFF + vr * 128 + (((4 + lg) ^ (vr & 7)) << 4));
        oacc[cv * 4 + dt] = mfma16(av0, pb0, oacc[cv * 4 + dt]);
        oacc[cv * 4 + dt] = mfma16(av1, pb1, oacc[cv * 4 + dt]);
      }
    }
  }
  // ---- finalize: divide by l, coalesced store of O^T rows
  float linv;
  {
    int src = (lm >> 2) << 4;
    float l0 = __shfl(lrow[0], src, 64);
    float l1 = __shfl(lrow[1], src, 64);
    float l2 = __shfl(lrow[2], src, 64);
    float l3 = __shfl(lrow[3], src, 64);
    int sel = lm & 3;
    float lv = sel == 0 ? l0 : sel == 1 ? l1 : sel == 2 ? l2 : l3;
    linv = 1.0f / lv;
  }
  const int s = qt * 64 + wv * 16 + lm;
  float* ob = out + ((size_t)b << 20) + s;
  #pragma unroll
  for (int f = 0; f < 32; ++f)
    #pragma unroll
    for (int i = 0; i < 4; ++i) {
      int d = f * 16 + lg * 4 + i;
      ob[(size_t)d * 2048] = oacc[f][i] * linv;
    }
}

// ---------------------------------------------------------------------------
extern "C" void kernel_launch(void* const* d_in, const int* in_sizes, int n_in,
                              void* d_out, int out_size, void* d_ws, size_t ws_size,
                              hipStream_t stream) {
  (void)in_sizes; (void)n_in; (void)out_size; (void)ws_size;
  const float* x  = (const float*)d_in[0];
  const float* Wk = (const float*)d_in[1];
  const float* Wq = (const float*)d_in[2];
  const float* Wv = (const float*)d_in[3];
  float* out = (float*)d_out;

  const size_t SZ = (size_t)16384 * 512;  // elements per [M][512] array
  u16* q_hi = (u16*)d_ws;
  u16* q_lo = q_hi + SZ;
  u16* k_hi = q_lo + SZ;
  u16* k_lo = k_hi + SZ;
  u16* v_t  = k_lo + SZ;                  // [8][512][2048] bf16

  (void)hipFuncSetAttribute(reinterpret_cast<const void*>(&proj_gemm<0>),
                            hipFuncAttributeMaxDynamicSharedMemorySize, 65536);
  (void)hipFuncSetAttribute(reinterpret_cast<const void*>(&proj_gemm<1>),
                            hipFuncAttributeMaxDynamicSharedMemorySize, 65536);
  (void)hipFuncSetAttribute(reinterpret_cast<const void*>(&attn_fused),
                            hipFuncAttributeMaxDynamicSharedMemorySize, 163840);

  dim3 blk(256);
  // q = 5 * x @ Wq^T (scale folded into q so scores come out pre-scaled)
  proj_gemm<0><<<dim3(4, 128), blk, 65536, stream>>>(x, Wq, q_hi, q_lo, 5.0f);
  proj_gemm<0><<<dim3(4, 128), blk, 65536, stream>>>(x, Wk, k_hi, k_lo, 1.0f);
  // v^T via swapped operands: C[d][token] = Wv[d][k] * x[token][k]^T
  proj_gemm<1><<<dim3(128, 4), blk, 65536, stream>>>(Wv, x, v_t, nullptr, 1.0f);
  attn_fused<<<dim3(32, 8), blk, 163840, stream>>>(q_hi, q_lo, k_hi, k_lo, v_t, out);
}

// Round 2
// 337.028 us; speedup vs baseline: 1.5290x; 1.5290x over previous
//
#include <hip/hip_runtime.h>
#include <stdint.h>

typedef __attribute__((ext_vector_type(4))) float f32x4;
typedef __attribute__((ext_vector_type(8))) short short8;
typedef unsigned short u16;
typedef unsigned int u32;

#define DEV static __device__ __forceinline__

DEV u32 fbits(float f) { union { float f; u32 u; } v; v.f = f; return v.u; }
DEV float bits2f(u32 u) { union { u32 u; float f; } v; v.u = u; return v.f; }

// bf16 round-to-nearest-even
DEV u16 f2bf_rne(float f) {
  u32 u = fbits(f);
  u32 r = u + 0x7fffu + ((u >> 16) & 1u);
  return (u16)(r >> 16);
}
DEV u16 f2bf_trunc(float f) { return (u16)(fbits(f) >> 16); }
DEV float bf2f(u16 h) { return bits2f(((u32)h) << 16); }

// split f32 -> hi (RNE) + lo (trunc of residual): hi+lo accurate to ~2^-17 rel
DEV void split2(float f, u16& h, u16& l) {
  h = f2bf_rne(f);
  float r = f - bf2f(h);
  l = f2bf_trunc(r);
}

DEV void gll16(const void* gsrc, char* ldsp) {
  __builtin_amdgcn_global_load_lds(
      (const __attribute__((address_space(1))) u32*)gsrc,
      (__attribute__((address_space(3))) u32*)ldsp,
      16, 0, 0);
}

DEV f32x4 mfma16(short8 a, short8 b, f32x4 c) {
  return __builtin_amdgcn_mfma_f32_16x16x32_bf16(a, b, c, 0, 0, 0);
}

// ---------------------------------------------------------------------------
// K1: C[M][N] = A[M][512] * B[N][512]^T in fp32-emulated (split bf16, 3 MFMA)
// EPI==0: write (scale*C) split into hi/lo bf16 arrays [M][512]   (q, k)
// EPI==1: write bf16(C) into v_t[b][d][s'] layout, m=d, n=global token (v),
//         with the PV contract permutation applied within each 32-col group.
// block 256 thr (4 waves), tile 128x128, BK=64, LDS 64KiB
// ---------------------------------------------------------------------------
template<int EPI>
__global__ __launch_bounds__(256, 1) void proj_gemm(
    const float* __restrict__ A, const float* __restrict__ Bm,
    u16* __restrict__ o0, u16* __restrict__ o1, float scale)
{
  extern __shared__ char smem[];
  const int tid = threadIdx.x;
  const int lane = tid & 63, wv = tid >> 6;
  const int wm = wv & 1, wn = wv >> 1;
  const int lm = lane & 15, lg = lane >> 4;
  const int n0 = blockIdx.x * 128, m0 = blockIdx.y * 128;

  f32x4 acc[4][4] = {};

  for (int k0 = 0; k0 < 512; k0 += 64) {
    __syncthreads();
    #pragma unroll
    for (int i = 0; i < 8; ++i) {
      int c = i * 256 + tid;          // f32x4 chunk 0..2047
      int row = c >> 4, c4 = c & 15;
      f32x4 av = *(const f32x4*)(A + (size_t)(m0 + row) * 512 + (k0 + c4 * 4));
      f32x4 bv = *(const f32x4*)(Bm + (size_t)(n0 + row) * 512 + (k0 + c4 * 4));
      int base = row * 128 + ((((c4 >> 1) ^ (row & 7)) << 4) + (c4 & 1) * 8);
      u16 ah[4], al[4], bh[4], bl[4];
      #pragma unroll
      for (int j = 0; j < 4; ++j) { split2(av[j], ah[j], al[j]); split2(bv[j], bh[j], bl[j]); }
      *(ushort4*)(smem +         base) = make_ushort4(ah[0], ah[1], ah[2], ah[3]);
      *(ushort4*)(smem + 16384 + base) = make_ushort4(al[0], al[1], al[2], al[3]);
      *(ushort4*)(smem + 32768 + base) = make_ushort4(bh[0], bh[1], bh[2], bh[3]);
      *(ushort4*)(smem + 49152 + base) = make_ushort4(bl[0], bl[1], bl[2], bl[3]);
    }
    __syncthreads();
    #pragma unroll
    for (int ks = 0; ks < 2; ++ks) {
      short8 fah[4], fal[4], fbh[4], fbl[4];
      #pragma unroll
      for (int t = 0; t < 4; ++t) {
        int ar = wm * 64 + t * 16 + lm;
        int ac = (((ks * 4 + lg) ^ (ar & 7)) << 4);
        fah[t] = *(const short8*)(smem +         ar * 128 + ac);
        fal[t] = *(const short8*)(smem + 16384 + ar * 128 + ac);
        int br = wn * 64 + t * 16 + lm;
        int bc = (((ks * 4 + lg) ^ (br & 7)) << 4);
        fbh[t] = *(const short8*)(smem + 32768 + br * 128 + bc);
        fbl[t] = *(const short8*)(smem + 49152 + br * 128 + bc);
      }
      #pragma unroll
      for (int mt = 0; mt < 4; ++mt)
        #pragma unroll
        for (int nt = 0; nt < 4; ++nt) {
          acc[mt][nt] = mfma16(fah[mt], fbh[nt], acc[mt][nt]);
          acc[mt][nt] = mfma16(fah[mt], fbl[nt], acc[mt][nt]);
          acc[mt][nt] = mfma16(fal[mt], fbh[nt], acc[mt][nt]);
        }
    }
  }
  // epilogue: C row = (lane>>4)*4 + i, col = lane&15
  #pragma unroll
  for (int mt = 0; mt < 4; ++mt)
    #pragma unroll
    for (int nt = 0; nt < 4; ++nt)
      #pragma unroll
      for (int i = 0; i < 4; ++i) {
        float v = acc[mt][nt][i] * scale;
        int m = m0 + wm * 64 + mt * 16 + lg * 4 + i;
        int n = n0 + wn * 64 + nt * 16 + lm;
        if (EPI == 0) {
          u16 h, l; split2(v, h, l);
          o0[(size_t)m * 512 + n] = h;
          o1[(size_t)m * 512 + n] = l;
        } else {
          // v_t[b][d][s']: permute key r=(n&31) -> col c within its 32-group
          int r = n & 31;
          int cc = ((r >> 2) & 3) * 8 + ((r >> 4) << 2) + (r & 3);
          int n2 = (n & ~31) | cc;
          size_t addr = ((size_t)(n >> 11) << 20) | ((size_t)m << 11) | (size_t)(n2 & 2047);
          o0[addr] = f2bf_rne(v);
        }
      }
}

// ---------------------------------------------------------------------------
// K2: fused flash attention, pipelined.
// 4 waves, 64 q-rows (16 q-cols per wave via swapped QK^T: S^T = K*Q^T).
// Q hi/lo resident in LDS (128KB). Per kt: 12 uniform 16KB chunks
// (8 K-chunks [64k][64d] hi+lo, 4 V-chunks [128d][64k]) double-buffered with
// raw s_barrier + counted vmcnt(4). Softmax fully lane-local (q-col = lm).
// P -> PV B-frags is a pure in-lane repack (contract permutation baked into
// v_t's column order by proj<1>). Computes O^T -> coalesced [B][D][S] store.
// LDS: QH 64K | QL 64K | STG0 16K | STG1 16K = 160KiB
// ---------------------------------------------------------------------------
#define QH_OFF 0
#define QL_OFF 65536
#define STG0   131072
#define STG1   147456

DEV void stage_chunk(const u16* __restrict__ kh, const u16* __restrict__ kl,
                     const u16* __restrict__ vt, char* smem, int buf,
                     int b, int kt, int c, int tid) {
  char* dst = smem + (buf ? STG1 : STG0);
  if (c < 8) {  // K chunk: khi [64k][64d] 8KB + klo 8KB
    const size_t kbase = (size_t)b * 2048 * 512 + (size_t)kt * 64 * 512 + c * 64;
    #pragma unroll
    for (int j = 0; j < 2; ++j) {
      int slot = j * 256 + tid;
      int r = slot >> 3, ch = slot & 7, sc = ch ^ (r & 7);
      size_t src = kbase + (size_t)r * 512 + sc * 8;
      gll16(kh + src, dst + slot * 16);
      gll16(kl + src, dst + 8192 + slot * 16);
    }
  } else {      // V chunk cv = c-8: [128 d][64 k] 16KB
    const int cv = c - 8;
    const size_t vbase = (size_t)b * 512 * 2048 + (size_t)(cv * 128) * 2048 + (size_t)kt * 64;
    #pragma unroll
    for (int j = 0; j < 4; ++j) {
      int slot = j * 256 + tid;
      int r = slot >> 3, ch = slot & 7, sc = ch ^ (r & 7);
      gll16(vt + vbase + (size_t)r * 2048 + sc * 8, dst + slot * 16);
    }
  }
}

__global__ __launch_bounds__(256, 1) void attn_fused(
    const u16* __restrict__ qh, const u16* __restrict__ ql,
    const u16* __restrict__ kh, const u16* __restrict__ kl,
    const u16* __restrict__ vt, float* __restrict__ out)
{
  extern __shared__ char smem[];
  const int tid = threadIdx.x;
  const int lane = tid & 63, wv = tid >> 6;
  const int lm = lane & 15, lg = lane >> 4;
  const int b = blockIdx.x, qt = blockIdx.y;   // grid (8,32): batch fastest -> XCD-local K/V

  // ---- stage Q hi/lo [64][512] bf16, swizzled (16B chunk ^= row&7)
  {
    const size_t qbase = (size_t)(b * 2048 + qt * 64) * 512;
    #pragma unroll
    for (int it = 0; it < 16; ++it) {
      int slot = it * 256 + tid;
      int row = slot >> 6, ch = slot & 63;
      int sc = ch ^ (row & 7);
      size_t src = qbase + (size_t)row * 512 + sc * 8;
      gll16(qh + src, smem + QH_OFF + slot * 16);
      gll16(ql + src, smem + QL_OFF + slot * 16);
    }
  }
  // ---- prologue: stage chunk (kt=0,c=0) into buf0
  stage_chunk(kh, kl, vt, smem, 0, b, 0, 0, tid);

  float m = -3e38f, l = 0.f;
  f32x4 oacc[32] = {};
  short8 pb0 = {}, pb1 = {};
  const int qrow = wv * 16 + lm;   // this wave's q-rows; lane's q-col = lm

  for (int kt = 0; kt < 32; ++kt) {
    f32x4 sacc[4] = {};
    #pragma unroll
    for (int c = 0; c < 12; ++c) {
      // ---- stage next chunk (wraps to kt+1 / kt0 harmlessly)
      {
        int nk = kt, nc = c + 1;
        if (nc == 12) { nc = 0; nk = (kt + 1) & 31; }
        stage_chunk(kh, kl, vt, smem, (c + 1) & 1, b, nk, nc, tid);
      }
      // ---- softmax + P repack between QK and PV phases (register-only)
      if (c == 8) {
        float mx = fmaxf(fmaxf(fmaxf(sacc[0][0], sacc[0][1]), fmaxf(sacc[0][2], sacc[0][3])),
                         fmaxf(fmaxf(sacc[1][0], sacc[1][1]), fmaxf(sacc[1][2], sacc[1][3])));
        mx = fmaxf(mx, fmaxf(fmaxf(fmaxf(sacc[2][0], sacc[2][1]), fmaxf(sacc[2][2], sacc[2][3])),
                             fmaxf(fmaxf(sacc[3][0], sacc[3][1]), fmaxf(sacc[3][2], sacc[3][3]))));
        mx = fmaxf(mx, __shfl_xor(mx, 16, 64));
        mx = fmaxf(mx, __shfl_xor(mx, 32, 64));
        if (__any(mx > m)) {          // exact rescale-skip: only when max grows
          float mn = fmaxf(m, mx);
          float alpha = __expf(m - mn);
          m = mn;
          #pragma unroll
          for (int f = 0; f < 32; ++f) {
            oacc[f][0] *= alpha; oacc[f][1] *= alpha;
            oacc[f][2] *= alpha; oacc[f][3] *= alpha;
          }
          l *= alpha;
        }
        float sm = 0.f;
        #pragma unroll
        for (int t4 = 0; t4 < 4; ++t4)
          #pragma unroll
          for (int i = 0; i < 4; ++i) {
            float p = __expf(sacc[t4][i] - m);
            sacc[t4][i] = p;
            sm += p;
          }
        sm += __shfl_xor(sm, 16, 64);
        sm += __shfl_xor(sm, 32, 64);
        l += sm;
        // pure in-lane P repack: pb[ks][j] = sacc[2ks + (j>>2)][j&3]
        #pragma unroll
        for (int j = 0; j < 4; ++j) {
          pb0[j]     = (short)f2bf_rne(sacc[0][j]);
          pb0[4 + j] = (short)f2bf_rne(sacc[1][j]);
          pb1[j]     = (short)f2bf_rne(sacc[2][j]);
          pb1[4 + j] = (short)f2bf_rne(sacc[3][j]);
        }
      }
      // ---- wait for current chunk (4 loads just issued stay in flight)
      asm volatile("s_waitcnt vmcnt(4)" ::: "memory");
      __builtin_amdgcn_s_barrier();
      __builtin_amdgcn_sched_barrier(0);
      const char* bufp = smem + ((c & 1) ? STG1 : STG0);
      if (c < 8) {
        // QK^T swapped: sacc[t4] (S^T tile [16k][16q]) += K*Q^T, 3-pass split
        #pragma unroll
        for (int ks = 0; ks < 2; ++ks) {
          int qg = c * 8 + ks * 4 + lg;
          short8 bqh = *(const short8*)(smem + QH_OFF + qrow * 1024 + ((qg ^ (qrow & 7)) << 4));
          short8 bql = *(const short8*)(smem + QL_OFF + qrow * 1024 + ((qg ^ (qrow & 7)) << 4));
          #pragma unroll
          for (int t4 = 0; t4 < 4; ++t4) {
            int krow = t4 * 16 + lm;
            int kc = ((ks * 4 + lg) ^ (krow & 7)) << 4;
            short8 akh = *(const short8*)(bufp + krow * 128 + kc);
            short8 akl = *(const short8*)(bufp + 8192 + krow * 128 + kc);
            sacc[t4] = mfma16(akh, bqh, sacc[t4]);
            sacc[t4] = mfma16(akh, bql, sacc[t4]);
            sacc[t4] = mfma16(akl, bqh, sacc[t4]);
          }
        }
      } else {
        const int cv = c - 8;
        #pragma unroll
        for (int dt = 0; dt < 8; ++dt) {
          int vrow = dt * 16 + lm;
          short8 av0 = *(const short8*)(bufp + vrow * 128 + ((lg ^ (vrow & 7)) << 4));
          short8 av1 = *(const short8*)(bufp + vrow * 128 + (((4 + lg) ^ (vrow & 7)) << 4));
          f32x4 o = oacc[cv * 8 + dt];
          o = mfma16(av0, pb0, o);
          o = mfma16(av1, pb1, o);
          oacc[cv * 8 + dt] = o;
        }
      }
      __builtin_amdgcn_sched_barrier(0);
      __builtin_amdgcn_s_barrier();
    }
  }
  // ---- finalize: divide by l (lane-local), coalesced O^T store
  float linv = 1.0f / l;
  const int s = qt * 64 + wv * 16 + lm;
  float* ob = out + ((size_t)b << 20) + s;
  #pragma unroll
  for (int f = 0; f < 32; ++f)
    #pragma unroll
    for (int i = 0; i < 4; ++i) {
      int d = f * 16 + lg * 4 + i;
      ob[(size_t)d * 2048] = oacc[f][i] * linv;
    }
}

// ---------------------------------------------------------------------------
extern "C" void kernel_launch(void* const* d_in, const int* in_sizes, int n_in,
                              void* d_out, int out_size, void* d_ws, size_t ws_size,
                              hipStream_t stream) {
  (void)in_sizes; (void)n_in; (void)out_size; (void)ws_size;
  const float* x  = (const float*)d_in[0];
  const float* Wk = (const float*)d_in[1];
  const float* Wq = (const float*)d_in[2];
  const float* Wv = (const float*)d_in[3];
  float* out = (float*)d_out;

  const size_t SZ = (size_t)16384 * 512;  // elements per [M][512] array
  u16* q_hi = (u16*)d_ws;
  u16* q_lo = q_hi + SZ;
  u16* k_hi = q_lo + SZ;
  u16* k_lo = k_hi + SZ;
  u16* v_t  = k_lo + SZ;                  // [8][512][2048] bf16 (col-permuted)

  (void)hipFuncSetAttribute(reinterpret_cast<const void*>(&proj_gemm<0>),
                            hipFuncAttributeMaxDynamicSharedMemorySize, 65536);
  (void)hipFuncSetAttribute(reinterpret_cast<const void*>(&proj_gemm<1>),
                            hipFuncAttributeMaxDynamicSharedMemorySize, 65536);
  (void)hipFuncSetAttribute(reinterpret_cast<const void*>(&attn_fused),
                            hipFuncAttributeMaxDynamicSharedMemorySize, 163840);

  dim3 blk(256);
  // q = 5 * x @ Wq^T (scale folded into q so scores come out pre-scaled)
  proj_gemm<0><<<dim3(4, 128), blk, 65536, stream>>>(x, Wq, q_hi, q_lo, 5.0f);
  proj_gemm<0><<<dim3(4, 128), blk, 65536, stream>>>(x, Wk, k_hi, k_lo, 1.0f);
  // v^T via swapped operands: C[d][token] = Wv[d][k] * x[token][k]^T
  proj_gemm<1><<<dim3(128, 4), blk, 65536, stream>>>(Wv, x, v_t, nullptr, 1.0f);
  attn_fused<<<dim3(8, 32), blk, 163840, stream>>>(q_hi, q_lo, k_hi, k_lo, v_t, out);
}